// Round 2
// 392.408 us; speedup vs baseline: 1.0037x; 1.0037x over previous
//
#include <hip/hip_runtime.h>

// Embedding gather: out[i, :] = table[ids[i], :]
// ids: int32 [819200]; table: f32 [1000000, 64]; out: f32 [819200, 64]
// Row = 256 B = 16 x float4.
//
// V2b: latency-bound fix (compile-fixed). Each thread handles 4 rows at the
// same float4-column:
//   - one int4 load fetches 4 ids
//   - 4 INDEPENDENT table float4 loads issued back-to-back (MLP x4)
//   - 4 nontemporal stores (output is write-once; keep LLC for the 256 MB
//     table whose repeat-touches we want cached)
// Native clang vector type used so __builtin_nontemporal_store accepts it.

typedef float f4 __attribute__((ext_vector_type(4)));

__global__ __launch_bounds__(256) void OnlineEmbedding_64484638982170_kernel(
    const int4* __restrict__ ids4,      // [N/4] packed ids
    const f4* __restrict__ table,       // [VOCAB * 16] float4
    f4* __restrict__ out,               // [N * 16] float4
    int n_grp)                          // N / 4
{
    int tid = blockIdx.x * blockDim.x + threadIdx.x;
    int col = tid & 15;          // float4 index within a row
    int grp = tid >> 4;          // which group of 4 rows
    if (grp >= n_grp) return;

    int4 id = ids4[grp];         // 4 row ids in one 16 B load

    const f4* t = table + col;
    // 4 independent random row-fetches in flight simultaneously
    f4 v0 = t[(long long)id.x * 16];
    f4 v1 = t[(long long)id.y * 16];
    f4 v2 = t[(long long)id.z * 16];
    f4 v3 = t[(long long)id.w * 16];

    f4* o = out + (size_t)grp * 64 + col;   // rows 4*grp .. 4*grp+3
    __builtin_nontemporal_store(v0, o);
    __builtin_nontemporal_store(v1, o + 16);
    __builtin_nontemporal_store(v2, o + 32);
    __builtin_nontemporal_store(v3, o + 48);
}

// Tail kernel for n_rows % 4 != 0 (not hit at N=819200, kept for safety).
__global__ __launch_bounds__(64) void OnlineEmbedding_64484638982170_tail(
    const int* __restrict__ ids,
    const f4* __restrict__ table,
    f4* __restrict__ out,
    int row_start, int n_rows)
{
    int tid = blockIdx.x * blockDim.x + threadIdx.x;
    int row = row_start + (tid >> 4);
    int col = tid & 15;
    if (row >= n_rows) return;
    long long id = (long long)ids[row];
    out[(size_t)row * 16 + col] = table[id * 16 + col];
}

extern "C" void kernel_launch(void* const* d_in, const int* in_sizes, int n_in,
                              void* d_out, int out_size, void* d_ws, size_t ws_size,
                              hipStream_t stream) {
    const int* ids   = (const int*)d_in[0];     // [BATCH*HIST] int32
    const f4* table  = (const f4*)d_in[1];      // [VOCAB, 64] f32 as float4
    f4* out          = (f4*)d_out;

    const int n_rows = in_sizes[0];        // 819200
    const int n_grp  = n_rows >> 2;        // groups of 4 rows
    const int rem    = n_rows & 3;

    const int block = 256;
    const int total_threads = n_grp * 16;  // one thread per (group, col)
    const int grid = (total_threads + block - 1) / block;
    if (grid > 0) {
        OnlineEmbedding_64484638982170_kernel<<<grid, block, 0, stream>>>(
            (const int4*)ids, table, out, n_grp);
    }
    if (rem) {
        OnlineEmbedding_64484638982170_tail<<<1, 64, 0, stream>>>(
            ids, table, out, n_grp * 4, n_rows);
    }
}